// Round 6
// baseline (321.302 us; speedup 1.0000x reference)
//
#include <hip/hip_runtime.h>

// Chunked linear attention (causal, unnormalized), bf16 MFMA, fp32 I/O.
// R9: carry-sum moved OUT of phB into a fixup kernel.
//   phA: split-scan, grid bh x slice x seg (64*8*2=1024), CPS=8, NSEG=2
//        (seg0 -> true H_1..H_7 at slots 1..7, T_0 at slot 0;
//         seg1 -> locals at slots 9..15; slot 8 untouched).
//   phFix: grid (bh, n=8..15): slot8 <- T_0; slots 9..15 <- local + T_0.
//        After phFix, slots 1..15 hold TRUE exclusive prefixes H_n.
//   phB: block=(bh,n,tb). R8 pipeline, but H stage is a single-slot
//        straight copy (no carry sum, no nmat divergence).
// B=4 S=2048 H=16 D=128. ws: 64*16*128*128 bf16 = 32 MiB.

#define Bc 4
#define Sq 2048
#define Hh 16
#define Dd 128
#define RS (Hh * Dd)      // 2048
#define Cc 128
#define NCH (Sq / Cc)     // 16
#define BHt (Bc * Hh)     // 64
#define NSEG 2
#define CPS (NCH / NSEG)  // 8
#define SCALE 0.08838834764831845f

using frag_ab = __attribute__((ext_vector_type(8))) short;  // 8 bf16
using frag_cd = __attribute__((ext_vector_type(4))) float;  // 4 fp32

__device__ __forceinline__ unsigned short f2bf(float f) {
  union { float f; unsigned u; } x; x.f = f;
  unsigned r = x.u + 0x7FFFu + ((x.u >> 16) & 1u);  // RNE
  return (unsigned short)(r >> 16);
}
__device__ __forceinline__ float bf2f(unsigned short u) {
  union { unsigned u; float f; } x; x.u = ((unsigned)u) << 16;
  return x.f;
}
// swizzles: permute 8-element (16 B) blocks within a row -> frag b128 reads
// stay contiguous; writes spread across banks.
__device__ __forceinline__ int sw64(int r, int c) {
  return r * 64 + ((((c >> 3) ^ (r & 7)) << 3) | (c & 7));
}
__device__ __forceinline__ int sw128(int r, int c) {
  return r * 128 + ((((c >> 3) ^ (r & 15)) << 3) | (c & 7));
}
__device__ __forceinline__ int swKT(int dk, int t) {  // [dk 128][t 128]
  return dk * 128 + ((((t >> 3) ^ (dk ^ (dk >> 4))) & 15) << 3) + (t & 7);
}
__device__ __forceinline__ int swVT(int dv, int t) {  // [dv 16][t 128]
  return dv * 128 + ((((t >> 3) ^ dv) & 15) << 3) + (t & 7);
}

// ---------- phA: split scan. Block = (bh, slice, seg); scans CPS chunks ----
// bid layout: bh low 6 bits (XCD-colocate), slice bits 6-8, seg bit 9.
__global__ __launch_bounds__(256) void phA_state(const float* __restrict__ kg,
                                                 const float* __restrict__ vg,
                                                 unsigned short* __restrict__ st) {
  __shared__ unsigned short KT[128 * 128];  // 32 KB [dk][t]
  __shared__ unsigned short VT[16 * 128];   //  4 KB [dv][t]
  const int tid = threadIdx.x;
  const int bh = blockIdx.x & 63;
  const int slice = (blockIdx.x >> 6) & 7;
  const int seg = blockIdx.x >> 9;
  const int b = bh >> 4, h = bh & 15;
  const int dv0 = slice * 16;
  const size_t base = (size_t)b * Sq * RS + (size_t)h * Dd;
  const int w = tid >> 6, L = tid & 63, li = L & 15, q4 = L >> 4;
  const int kdk0 = (tid & 31) * 4;
  const int ktg4 = (tid >> 5) * 4;
  const int vdv0l = (tid & 3) * 4;
  const int vt0 = (tid >> 2) * 2;

  float4 rk[4][4];
  float4 rv[2];
  auto prefetch = [&](int n) {
    const size_t t0g = (size_t)n * Cc;
#pragma unroll
    for (int p = 0; p < 4; ++p) {
      const int t0 = p * 32 + ktg4;
#pragma unroll
      for (int i = 0; i < 4; ++i)
        rk[p][i] = *(const float4*)(kg + base + (t0g + t0 + i) * (size_t)RS + kdk0);
    }
#pragma unroll
    for (int i = 0; i < 2; ++i)
      rv[i] = *(const float4*)(vg + base + (t0g + vt0 + i) * (size_t)RS + dv0 + vdv0l);
  };

  frag_cd acc[2];
  acc[0] = (frag_cd){0.f, 0.f, 0.f, 0.f};
  acc[1] = (frag_cd){0.f, 0.f, 0.f, 0.f};
  const int n0 = seg * CPS;
  prefetch(n0);
  const size_t sbb = (size_t)bh * NCH * (128 * 128);

  auto store_acc = [&](int slot) {
    const size_t sb = sbb + (size_t)slot * (128 * 128);
#pragma unroll
    for (int nt = 0; nt < 2; ++nt)
#pragma unroll
      for (int r = 0; r < 4; ++r) {
        const int dv = dv0 + 4 * q4 + r;
        const int dk = 32 * w + 16 * nt + li;
        st[sb + (size_t)dv * 128 + dk] = f2bf(acc[nt][r]);
      }
  };

  for (int j = 0; j < CPS; ++j) {
    __syncthreads();  // prev chunk's frag reads done
#pragma unroll
    for (int p = 0; p < 4; ++p) {
      const int t0 = p * 32 + ktg4;
#pragma unroll
      for (int jj = 0; jj < 4; ++jj) {
        ushort4 u;
        u.x = f2bf(((const float*)&rk[p][0])[jj]);
        u.y = f2bf(((const float*)&rk[p][1])[jj]);
        u.z = f2bf(((const float*)&rk[p][2])[jj]);
        u.w = f2bf(((const float*)&rk[p][3])[jj]);
        *(ushort4*)&KT[swKT(kdk0 + jj, t0)] = u;
      }
    }
#pragma unroll
    for (int jj = 0; jj < 4; ++jj) {
      ushort2 u;
      u.x = f2bf(((const float*)&rv[0])[jj]);
      u.y = f2bf(((const float*)&rv[1])[jj]);
      *(ushort2*)&VT[swVT(vdv0l + jj, vt0)] = u;
    }
    if (j + 1 < CPS) prefetch(n0 + j + 1);  // HBM latency hides under LDS+MFMA
    __syncthreads();
    if (j > 0) store_acc(n0 + j);  // local EXCLUSIVE prefix
#pragma unroll
    for (int kt = 0; kt < 4; ++kt) {
      frag_ab af = *(const frag_ab*)&VT[swVT(li, 32 * kt + 8 * q4)];
#pragma unroll
      for (int nt = 0; nt < 2; ++nt) {
        frag_ab bf = *(const frag_ab*)&KT[swKT(32 * w + 16 * nt + li, 32 * kt + 8 * q4)];
        acc[nt] = __builtin_amdgcn_mfma_f32_16x16x32_bf16(af, bf, acc[nt], 0, 0, 0);
      }
    }
  }
  if (seg + 1 < NSEG) store_acc(n0);  // segment total T_0 -> slot 0
}

// ---------- phFix: slots 8..15 -> true exclusive prefixes ----------
// Block = (bh, slot n in 8..15). slot8 <- T_0 (slot0 copy);
// slots 9..15 <- local + T_0 (bf16 pairs summed in fp32, repacked).
// Slot 0 is read-only here; each block owns its written slot -> race-free.
__global__ __launch_bounds__(256) void phFix(unsigned short* __restrict__ st) {
  const int bh = blockIdx.x & 63, n8 = blockIdx.x >> 6;  // 0..7
  const int n = 8 + n8;
  const int tid = threadIdx.x;
  const size_t b0 = ((size_t)(bh * NCH + 0)) << 14;
  const size_t bn = ((size_t)(bh * NCH + n)) << 14;
#pragma unroll
  for (int i = 0; i < 8; ++i) {
    const size_t off = (size_t)i * 2048 + tid * 8;
    const uint4 t0 = *(const uint4*)(st + b0 + off);
    if (n8 == 0) {
      *(uint4*)(st + bn + off) = t0;
    } else {
      const uint4 ln = *(const uint4*)(st + bn + off);
      const unsigned a[4] = {ln.x, ln.y, ln.z, ln.w};
      const unsigned c[4] = {t0.x, t0.y, t0.z, t0.w};
      unsigned pk[4];
#pragma unroll
      for (int e = 0; e < 4; ++e) {
        const float lo = bf2f((unsigned short)(a[e] & 0xFFFFu)) +
                         bf2f((unsigned short)(c[e] & 0xFFFFu));
        const float hi = bf2f((unsigned short)(a[e] >> 16)) +
                         bf2f((unsigned short)(c[e] >> 16));
        pk[e] = (unsigned)f2bf(lo) | ((unsigned)f2bf(hi) << 16);
      }
      uint4 out; out.x = pk[0]; out.y = pk[1]; out.z = pk[2]; out.w = pk[3];
      *(uint4*)(st + bn + off) = out;
    }
  }
}

// ---------- phB: O = Qs*H_n + tril(Qs*K^T)*V, 64 query rows per block ----
// H_n = slot n directly (phFix made all slots true prefixes). Pipelined.
__global__ __launch_bounds__(256) void phB_out(const float* __restrict__ qg,
                                               const float* __restrict__ kg,
                                               const float* __restrict__ vg,
                                               const unsigned short* __restrict__ st,
                                               float* __restrict__ o) {
  __shared__ unsigned short QP[64 * 128];     // 16 KB: Qs rows of this tb, later P
  __shared__ unsigned short Bb[2][128 * 64];  // 2 x 16 KB ping-pong stages
  const int tid = threadIdx.x;
  const int bid = blockIdx.x;
  const int bh = bid & 63, n = (bid >> 6) & 15, tb = bid >> 10;
  const int b = bh >> 4, h = bh & 15;
  const size_t cbase = (size_t)b * Sq * RS + (size_t)n * Cc * RS + (size_t)h * Dd;
  const size_t tbase = cbase + (size_t)(64 * tb) * RS;
  const size_t sbh = (size_t)bh * NCH * (128 * 128);
  const int hasH = (n > 0);
  const int w = tid >> 6, L = tid & 63;
  const int wr = w >> 1, wc = w & 1, li = L & 15, q4 = L >> 4;

  frag_cd accO[2][4], accP[2][4];
#pragma unroll
  for (int i = 0; i < 2; ++i)
#pragma unroll
    for (int j = 0; j < 4; ++j) {
      accO[i][j] = (frag_cd){0.f, 0.f, 0.f, 0.f};
      accP[i][j] = (frag_cd){0.f, 0.f, 0.f, 0.f};
    }

  float4 sA[8], sB[8];     // K/V staging regs
  uint4 hA[4], hB[4];      // H staging regs (single slot)

  // ---- staging lambdas (load = issue global->reg; write = reg->LDS) ----
  auto loadK = [&](int half, float4 (&s)[8]) {
#pragma unroll
    for (int it = 0; it < 8; ++it) {
      const int f = it * 256 + tid;
      const int t = f >> 4;
      const int c0 = (f & 15) << 2;
      s[it] = *(const float4*)(kg + cbase + (size_t)t * RS + 64 * half + c0);
    }
  };
  auto writeK = [&](const float4 (&s)[8], unsigned short* bb) {
#pragma unroll
    for (int it = 0; it < 8; ++it) {
      const int f = it * 256 + tid;
      const int t = f >> 4;
      const int c0 = (f & 15) << 2;
      ushort4 ku;
      ku.x = f2bf(s[it].x); ku.y = f2bf(s[it].y);
      ku.z = f2bf(s[it].z); ku.w = f2bf(s[it].w);
      *(ushort4*)&bb[sw64(t, c0)] = ku;
    }
  };
  auto loadV = [&](int half, float4 (&s)[8]) {
#pragma unroll
    for (int it = 0; it < 8; ++it) {
      const int sl = (tid & 15) | ((it & 3) << 4);
      const int c0 = ((tid >> 4) | ((it >> 2) << 4)) << 2;
      const int sd = 64 * half + sl;
      s[it] = *(const float4*)(vg + cbase + (size_t)sd * RS + c0);
    }
  };
  auto writeV = [&](const float4 (&s)[8], unsigned short* bb) {
#pragma unroll
    for (int it = 0; it < 8; ++it) {
      const int sl = (tid & 15) | ((it & 3) << 4);
      const int c0 = ((tid >> 4) | ((it >> 2) << 4)) << 2;
      bb[sw64(c0 + 0, sl)] = f2bf(s[it].x);
      bb[sw64(c0 + 1, sl)] = f2bf(s[it].y);
      bb[sw64(c0 + 2, sl)] = f2bf(s[it].z);
      bb[sw64(c0 + 3, sl)] = f2bf(s[it].w);
    }
  };
  auto loadH = [&](int half, uint4 (&hr)[4]) {
    const size_t sb = sbh + ((size_t)n << 14);
#pragma unroll
    for (int it = 0; it < 4; ++it) {
      const int f = it * 256 + tid;
      const int dv = f >> 3;
      const int c8 = (f & 7) << 3;
      hr[it] = *(const uint4*)(st + sb + (size_t)dv * 128 + 64 * half + c8);
    }
  };
  auto writeH = [&](const uint4 (&hr)[4], unsigned short* bb) {
#pragma unroll
    for (int it = 0; it < 4; ++it) {
      const int f = it * 256 + tid;
      const int dv = f >> 3;
      const int c8 = (f & 7) << 3;
      *(uint4*)&bb[sw64(dv, c8)] = hr[it];
    }
  };

  // ---- compute lambdas ----
  auto gemmO = [&](const unsigned short* bb, int half) {
#pragma unroll
    for (int kt = 0; kt < 2; ++kt) {
      const int ktg = 2 * half + kt;
      frag_ab af[2], bf_[4];
#pragma unroll
      for (int mt = 0; mt < 2; ++mt)
        af[mt] = *(const frag_ab*)&QP[sw128(32 * wr + 16 * mt + li, 32 * ktg + 8 * q4)];
#pragma unroll
      for (int nt = 0; nt < 4; ++nt)
        bf_[nt] = *(const frag_ab*)&bb[sw64(64 * wc + 16 * nt + li, 32 * kt + 8 * q4)];
#pragma unroll
      for (int mt = 0; mt < 2; ++mt)
#pragma unroll
        for (int nt = 0; nt < 4; ++nt)
          accO[mt][nt] = __builtin_amdgcn_mfma_f32_16x16x32_bf16(af[mt], bf_[nt], accO[mt][nt], 0, 0, 0);
    }
  };
  auto gemmP = [&](const unsigned short* bb, int half) {
    if (64 * wc <= 64 * tb + 32 * wr + 31) {
#pragma unroll
      for (int kt = 0; kt < 2; ++kt) {
        const int ktg = 2 * half + kt;
        frag_ab af[2], bf_[4];
#pragma unroll
        for (int mt = 0; mt < 2; ++mt)
          af[mt] = *(const frag_ab*)&QP[sw128(32 * wr + 16 * mt + li, 32 * ktg + 8 * q4)];
#pragma unroll
        for (int nt = 0; nt < 4; ++nt)
          bf_[nt] = *(const frag_ab*)&bb[sw64(64 * wc + 16 * nt + li, 32 * kt + 8 * q4)];
#pragma unroll
        for (int mt = 0; mt < 2; ++mt)
#pragma unroll
          for (int nt = 0; nt < 4; ++nt)
            if (64 * wc + 16 * nt <= 64 * tb + 32 * wr + 16 * mt + 15)
              accP[mt][nt] = __builtin_amdgcn_mfma_f32_16x16x32_bf16(af[mt], bf_[nt], accP[mt][nt], 0, 0, 0);
      }
    }
  };
  auto gemmV = [&](const unsigned short* bb, int half) {
#pragma unroll
    for (int kt = 0; kt < 2; ++kt) {
      const int ktg = 2 * half + kt;
      if (32 * ktg > 64 * tb + 32 * wr + 31) continue;
      frag_ab af[2], bf_[4];
#pragma unroll
      for (int mt = 0; mt < 2; ++mt)
        af[mt] = *(const frag_ab*)&QP[sw128(32 * wr + 16 * mt + li, 32 * ktg + 8 * q4)];
#pragma unroll
      for (int nt = 0; nt < 4; ++nt)
        bf_[nt] = *(const frag_ab*)&bb[sw64(64 * wc + 16 * nt + li, 32 * kt + 8 * q4)];
#pragma unroll
      for (int mt = 0; mt < 2; ++mt)
#pragma unroll
        for (int nt = 0; nt < 4; ++nt)
          if (32 * ktg <= 64 * tb + 32 * wr + 16 * mt + 15)
            accO[mt][nt] = __builtin_amdgcn_mfma_f32_16x16x32_bf16(af[mt], bf_[nt], accO[mt][nt], 0, 0, 0);
    }
  };
  auto pwrite = [&]() {
#pragma unroll
    for (int mt = 0; mt < 2; ++mt)
#pragma unroll
      for (int nt = 0; nt < 4; ++nt) {
        const int t0 = 32 * wr + 16 * mt + 4 * q4;
        const int s = 64 * wc + 16 * nt + li;
#pragma unroll
        for (int r = 0; r < 4; ++r) {
          const int t = t0 + r;
          QP[sw128(t, s)] = (s <= t + 64 * tb) ? f2bf(accP[mt][nt][r]) : (unsigned short)0;
        }
      }
  };

  // ---- prologue: Q -> QP; K0 -> buf0; issue K1 ----
  {
    float4 qr[8];
#pragma unroll
    for (int it = 0; it < 8; ++it) {
      const int f = it * 256 + tid;
      const int t = f >> 5;
      const int c0 = (f & 31) << 2;
      qr[it] = *(const float4*)(qg + tbase + (size_t)t * RS + c0);
    }
    loadK(0, sA);
#pragma unroll
    for (int it = 0; it < 8; ++it) {
      const int f = it * 256 + tid;
      const int t = f >> 5;
      const int c0 = (f & 31) << 2;
      ushort4 qu;
      qu.x = f2bf(qr[it].x * SCALE); qu.y = f2bf(qr[it].y * SCALE);
      qu.z = f2bf(qr[it].z * SCALE); qu.w = f2bf(qr[it].w * SCALE);
      *(ushort4*)&QP[sw128(t, c0)] = qu;
    }
    loadK(1, sB);
    writeK(sA, Bb[0]);
  }
  __syncthreads();

  if (hasH) {
    // S0: QK dk-half0 (buf0); stage K1 -> buf1; issue H0
    loadH(0, hA);
    writeK(sB, Bb[1]);
    gemmP(Bb[0], 0);
    __syncthreads();
    // S1: QK dk-half1 (buf1); stage H0 -> buf0; issue H1
    loadH(1, hB);
    writeH(hA, Bb[0]);
    gemmP(Bb[1], 1);
    __syncthreads();
    // S2: H-GEMM dk-half0 (buf0); stage H1 -> buf1; issue V0
    loadV(0, sA);
    writeH(hB, Bb[1]);
    gemmO(Bb[0], 0);
    __syncthreads();
    // S3: H-GEMM dk-half1 (buf1); stage V0 -> buf0; issue V1 (tb=1)
    if (tb) loadV(1, sB);
    writeV(sA, Bb[0]);
    gemmO(Bb[1], 1);
    __syncthreads();
    // SP: all QP (Q) reads done -> overwrite with P
    pwrite();
    __syncthreads();
    // S4: PV s-half0 (buf0); stage V1 -> buf1 (tb=1)
    if (tb) writeV(sB, Bb[1]);
    gemmV(Bb[0], 0);
    if (tb) {
      __syncthreads();
      // S5: PV s-half1 (buf1)
      gemmV(Bb[1], 1);
    }
  } else {
    // n==0: no H-GEMM.
    // S0: QK dk-half0 (buf0); stage K1 -> buf1; issue V0
    loadV(0, sA);
    writeK(sB, Bb[1]);
    gemmP(Bb[0], 0);
    __syncthreads();
    // S1: QK dk-half1 (buf1); stage V0 -> buf0; issue V1 (tb=1)
    if (tb) loadV(1, sB);
    writeV(sA, Bb[0]);
    gemmP(Bb[1], 1);
    __syncthreads();
    pwrite();
    __syncthreads();
    // S2: PV s-half0 (buf0); stage V1 -> buf1 (tb=1)
    if (tb) writeV(sB, Bb[1]);
    gemmV(Bb[0], 0);
    if (tb) {
      __syncthreads();
      gemmV(Bb[1], 1);
    }
  }

  // store O fp32 (single write, no RMW)
#pragma unroll
  for (int mt = 0; mt < 2; ++mt)
#pragma unroll
    for (int nt = 0; nt < 4; ++nt)
#pragma unroll
      for (int r = 0; r < 4; ++r) {
        const int t = 32 * wr + 16 * mt + 4 * q4 + r;
        const int dv = 64 * wc + 16 * nt + li;
        o[tbase + (size_t)t * RS + dv] = accO[mt][nt][r];
      }
}

extern "C" void kernel_launch(void* const* d_in, const int* in_sizes, int n_in,
                              void* d_out, int out_size, void* d_ws, size_t ws_size,
                              hipStream_t stream) {
  const float* q = (const float*)d_in[0];
  const float* k = (const float*)d_in[1];
  const float* v = (const float*)d_in[2];
  float* o = (float*)d_out;
  unsigned short* st = (unsigned short*)d_ws;  // 32 MiB
  hipLaunchKernelGGL(phA_state, dim3(BHt * 8 * NSEG), dim3(256), 0, stream, k, v, st);
  hipLaunchKernelGGL(phFix, dim3(BHt * 8), dim3(256), 0, stream, st);
  hipLaunchKernelGGL(phB_out, dim3(BHt * NCH * 2), dim3(256), 0, stream, q, k, v, st, o);
}

// Round 7
// 286.352 us; speedup vs baseline: 1.1221x; 1.1221x over previous
//
#include <hip/hip_runtime.h>

// Chunked linear attention (causal, unnormalized), bf16 MFMA, fp32 I/O.
// R10: proven pieces only.
//   phA: split-scan (R9, unchanged): grid bh x slice x seg, NSEG=2, CPS=8.
//        seg0 -> true H_1..H_7 at slots 1..7, T_0 at slot 0;
//        seg1 -> locals at slots 9..15; slot 8 untouched.
//   phFix (R9, unchanged): slot8 <- T_0; slots 9..15 <- local + T_0.
//        After phFix, slots 1..15 hold TRUE exclusive prefixes H_n.
//   phB: R0's original monolithic 128-row kernel (fastest measured, <=83.8us,
//        no spills) + `if (n)` guard: slot 0 holds T_0 (not zeros), so n=0
//        skips the H-GEMM entirely. No reg-pipeline (R7/R8/R9 all spilled
//        or regressed), no tb split (duplicated K/V traffic, R5 = 98us).
// B=4 S=2048 H=16 D=128. ws: 64*16*128*128 bf16 = 32 MiB.

#define Bc 4
#define Sq 2048
#define Hh 16
#define Dd 128
#define RS (Hh * Dd)      // 2048
#define Cc 128
#define NCH (Sq / Cc)     // 16
#define BHt (Bc * Hh)     // 64
#define NSEG 2
#define CPS (NCH / NSEG)  // 8
#define SCALE 0.08838834764831845f

using frag_ab = __attribute__((ext_vector_type(8))) short;  // 8 bf16
using frag_cd = __attribute__((ext_vector_type(4))) float;  // 4 fp32

__device__ __forceinline__ unsigned short f2bf(float f) {
  union { float f; unsigned u; } x; x.f = f;
  unsigned r = x.u + 0x7FFFu + ((x.u >> 16) & 1u);  // RNE
  return (unsigned short)(r >> 16);
}
__device__ __forceinline__ float bf2f(unsigned short u) {
  union { unsigned u; float f; } x; x.u = ((unsigned)u) << 16;
  return x.f;
}
// swizzles: permute 8-element (16 B) blocks within a row -> frag b128 reads
// stay contiguous; writes spread across banks.
__device__ __forceinline__ int sw64(int r, int c) {
  return r * 64 + ((((c >> 3) ^ (r & 7)) << 3) | (c & 7));
}
__device__ __forceinline__ int sw128(int r, int c) {
  return r * 128 + ((((c >> 3) ^ (r & 15)) << 3) | (c & 7));
}
__device__ __forceinline__ int swKT(int dk, int t) {  // [dk 128][t 128]
  return dk * 128 + ((((t >> 3) ^ (dk ^ (dk >> 4))) & 15) << 3) + (t & 7);
}
__device__ __forceinline__ int swVT(int dv, int t) {  // [dv 16][t 128]
  return dv * 128 + ((((t >> 3) ^ dv) & 15) << 3) + (t & 7);
}

// ---------- phA: split scan. Block = (bh, slice, seg); scans CPS chunks ----
// bid layout: bh low 6 bits (XCD-colocate), slice bits 6-8, seg bit 9.
__global__ __launch_bounds__(256) void phA_state(const float* __restrict__ kg,
                                                 const float* __restrict__ vg,
                                                 unsigned short* __restrict__ st) {
  __shared__ unsigned short KT[128 * 128];  // 32 KB [dk][t]
  __shared__ unsigned short VT[16 * 128];   //  4 KB [dv][t]
  const int tid = threadIdx.x;
  const int bh = blockIdx.x & 63;
  const int slice = (blockIdx.x >> 6) & 7;
  const int seg = blockIdx.x >> 9;
  const int b = bh >> 4, h = bh & 15;
  const int dv0 = slice * 16;
  const size_t base = (size_t)b * Sq * RS + (size_t)h * Dd;
  const int w = tid >> 6, L = tid & 63, li = L & 15, q4 = L >> 4;
  const int kdk0 = (tid & 31) * 4;
  const int ktg4 = (tid >> 5) * 4;
  const int vdv0l = (tid & 3) * 4;
  const int vt0 = (tid >> 2) * 2;

  float4 rk[4][4];
  float4 rv[2];
  auto prefetch = [&](int n) {
    const size_t t0g = (size_t)n * Cc;
#pragma unroll
    for (int p = 0; p < 4; ++p) {
      const int t0 = p * 32 + ktg4;
#pragma unroll
      for (int i = 0; i < 4; ++i)
        rk[p][i] = *(const float4*)(kg + base + (t0g + t0 + i) * (size_t)RS + kdk0);
    }
#pragma unroll
    for (int i = 0; i < 2; ++i)
      rv[i] = *(const float4*)(vg + base + (t0g + vt0 + i) * (size_t)RS + dv0 + vdv0l);
  };

  frag_cd acc[2];
  acc[0] = (frag_cd){0.f, 0.f, 0.f, 0.f};
  acc[1] = (frag_cd){0.f, 0.f, 0.f, 0.f};
  const int n0 = seg * CPS;
  prefetch(n0);
  const size_t sbb = (size_t)bh * NCH * (128 * 128);

  auto store_acc = [&](int slot) {
    const size_t sb = sbb + (size_t)slot * (128 * 128);
#pragma unroll
    for (int nt = 0; nt < 2; ++nt)
#pragma unroll
      for (int r = 0; r < 4; ++r) {
        const int dv = dv0 + 4 * q4 + r;
        const int dk = 32 * w + 16 * nt + li;
        st[sb + (size_t)dv * 128 + dk] = f2bf(acc[nt][r]);
      }
  };

  for (int j = 0; j < CPS; ++j) {
    __syncthreads();  // prev chunk's frag reads done
#pragma unroll
    for (int p = 0; p < 4; ++p) {
      const int t0 = p * 32 + ktg4;
#pragma unroll
      for (int jj = 0; jj < 4; ++jj) {
        ushort4 u;
        u.x = f2bf(((const float*)&rk[p][0])[jj]);
        u.y = f2bf(((const float*)&rk[p][1])[jj]);
        u.z = f2bf(((const float*)&rk[p][2])[jj]);
        u.w = f2bf(((const float*)&rk[p][3])[jj]);
        *(ushort4*)&KT[swKT(kdk0 + jj, t0)] = u;
      }
    }
#pragma unroll
    for (int jj = 0; jj < 4; ++jj) {
      ushort2 u;
      u.x = f2bf(((const float*)&rv[0])[jj]);
      u.y = f2bf(((const float*)&rv[1])[jj]);
      *(ushort2*)&VT[swVT(vdv0l + jj, vt0)] = u;
    }
    if (j + 1 < CPS) prefetch(n0 + j + 1);  // HBM latency hides under LDS+MFMA
    __syncthreads();
    if (j > 0) store_acc(n0 + j);  // local EXCLUSIVE prefix
#pragma unroll
    for (int kt = 0; kt < 4; ++kt) {
      frag_ab af = *(const frag_ab*)&VT[swVT(li, 32 * kt + 8 * q4)];
#pragma unroll
      for (int nt = 0; nt < 2; ++nt) {
        frag_ab bf = *(const frag_ab*)&KT[swKT(32 * w + 16 * nt + li, 32 * kt + 8 * q4)];
        acc[nt] = __builtin_amdgcn_mfma_f32_16x16x32_bf16(af, bf, acc[nt], 0, 0, 0);
      }
    }
  }
  if (seg + 1 < NSEG) store_acc(n0);  // segment total T_0 -> slot 0
}

// ---------- phFix: slots 8..15 -> true exclusive prefixes ----------
// Block = (bh, slot n in 8..15). slot8 <- T_0 (slot0 copy);
// slots 9..15 <- local + T_0 (bf16 pairs summed in fp32, repacked).
// Slot 0 is read-only here; each block owns its written slot -> race-free.
__global__ __launch_bounds__(256) void phFix(unsigned short* __restrict__ st) {
  const int bh = blockIdx.x & 63, n8 = blockIdx.x >> 6;  // 0..7
  const int n = 8 + n8;
  const int tid = threadIdx.x;
  const size_t b0 = ((size_t)(bh * NCH + 0)) << 14;
  const size_t bn = ((size_t)(bh * NCH + n)) << 14;
#pragma unroll
  for (int i = 0; i < 8; ++i) {
    const size_t off = (size_t)i * 2048 + tid * 8;
    const uint4 t0 = *(const uint4*)(st + b0 + off);
    if (n8 == 0) {
      *(uint4*)(st + bn + off) = t0;
    } else {
      const uint4 ln = *(const uint4*)(st + bn + off);
      const unsigned a[4] = {ln.x, ln.y, ln.z, ln.w};
      const unsigned c[4] = {t0.x, t0.y, t0.z, t0.w};
      unsigned pk[4];
#pragma unroll
      for (int e = 0; e < 4; ++e) {
        const float lo = bf2f((unsigned short)(a[e] & 0xFFFFu)) +
                         bf2f((unsigned short)(c[e] & 0xFFFFu));
        const float hi = bf2f((unsigned short)(a[e] >> 16)) +
                         bf2f((unsigned short)(c[e] >> 16));
        pk[e] = (unsigned)f2bf(lo) | ((unsigned)f2bf(hi) << 16);
      }
      uint4 out; out.x = pk[0]; out.y = pk[1]; out.z = pk[2]; out.w = pk[3];
      *(uint4*)(st + bn + off) = out;
    }
  }
}

// ---------- phB: O = Qs*H_n + tril(Qs*K^T)*V (R0 structure) ----------
// Slot n holds the TRUE exclusive prefix (phFix). n==0 skips the H-GEMM
// (slot 0 holds T_0, not zeros). n is block-uniform -> barriers stay uniform.
__global__ __launch_bounds__(256) void phB_out(const float* __restrict__ qg,
                                               const float* __restrict__ kg,
                                               const float* __restrict__ vg,
                                               const unsigned short* __restrict__ st,
                                               float* __restrict__ o) {
  __shared__ unsigned short QP[128 * 128];  // 32 KB: Qs, later P
  __shared__ unsigned short Bb[128 * 64];   // 16 KB: H / K / V^T halves
  const int tid = threadIdx.x;
  const int bid = blockIdx.x;
  const int bh = bid >> 4, n = bid & 15;
  const int b = bh >> 4, h = bh & 15;
  const size_t cbase = (size_t)b * Sq * RS + (size_t)n * Cc * RS + (size_t)h * Dd;
  const size_t sb = (size_t)(bh * 16 + n) * (128 * 128);
  const int w = tid >> 6, L = tid & 63;
  const int wr = w >> 1, wc = w & 1, li = L & 15, q4 = L >> 4;

  // stage Qs full (scaled) -> QP
#pragma unroll
  for (int it = 0; it < 16; ++it) {
    const int f = it * 256 + tid;
    const int t = f >> 5;
    const int c0 = (f & 31) << 2;
    const float4 q4v = *(const float4*)(qg + cbase + (size_t)t * RS + c0);
    ushort4 qu;
    qu.x = f2bf(q4v.x * SCALE); qu.y = f2bf(q4v.y * SCALE);
    qu.z = f2bf(q4v.z * SCALE); qu.w = f2bf(q4v.w * SCALE);
    *(ushort4*)&QP[sw128(t, c0)] = qu;
  }
  frag_cd accO[4][4], accP[4][4];
#pragma unroll
  for (int i = 0; i < 4; ++i)
#pragma unroll
    for (int j = 0; j < 4; ++j) {
      accO[i][j] = (frag_cd){0.f, 0.f, 0.f, 0.f};
      accP[i][j] = (frag_cd){0.f, 0.f, 0.f, 0.f};
    }

  // ---- H-GEMM: accO = Qs (from QP) x H  (H in ws is [dv][dk]) ----
  if (n) {
    for (int half = 0; half < 2; ++half) {
      __syncthreads();  // half0: QP visible; half1: Bb reads done
#pragma unroll
      for (int it = 0; it < 4; ++it) {
        const int f = it * 256 + tid;
        const int dv = f >> 3;
        const int c8 = (f & 7) << 3;
        const uint4 hv = *(const uint4*)(st + sb + (size_t)dv * 128 + 64 * half + c8);
        *(uint4*)&Bb[sw64(dv, c8)] = hv;
      }
      __syncthreads();
#pragma unroll
      for (int kt = 0; kt < 2; ++kt) {
        const int ktg = 2 * half + kt;
        frag_ab af[4], bf_[4];
#pragma unroll
        for (int mt = 0; mt < 4; ++mt)
          af[mt] = *(const frag_ab*)&QP[sw128(64 * wr + 16 * mt + li, 32 * ktg + 8 * q4)];
#pragma unroll
        for (int nt = 0; nt < 4; ++nt)
          bf_[nt] = *(const frag_ab*)&Bb[sw64(64 * wc + 16 * nt + li, 32 * kt + 8 * q4)];
#pragma unroll
        for (int mt = 0; mt < 4; ++mt)
#pragma unroll
          for (int nt = 0; nt < 4; ++nt)
            accO[mt][nt] = __builtin_amdgcn_mfma_f32_16x16x32_bf16(af[mt], bf_[nt], accO[mt][nt], 0, 0, 0);
      }
    }
  }

  // ---- GEMM1: accP = Qs x K^T (triangle-skipped) ----
  for (int half = 0; half < 2; ++half) {
    __syncthreads();
#pragma unroll
    for (int it = 0; it < 8; ++it) {
      const int f = it * 256 + tid;
      const int t = f >> 4;
      const int c0 = (f & 15) << 2;
      const float4 k4v = *(const float4*)(kg + cbase + (size_t)t * RS + 64 * half + c0);
      ushort4 ku;
      ku.x = f2bf(k4v.x); ku.y = f2bf(k4v.y); ku.z = f2bf(k4v.z); ku.w = f2bf(k4v.w);
      *(ushort4*)&Bb[sw64(t, c0)] = ku;
    }
    __syncthreads();
    if (64 * wc <= 64 * wr + 63) {
#pragma unroll
      for (int kt = 0; kt < 2; ++kt) {
        const int ktg = 2 * half + kt;
        frag_ab af[4], bf_[4];
#pragma unroll
        for (int mt = 0; mt < 4; ++mt)
          af[mt] = *(const frag_ab*)&QP[sw128(64 * wr + 16 * mt + li, 32 * ktg + 8 * q4)];
#pragma unroll
        for (int nt = 0; nt < 4; ++nt)
          bf_[nt] = *(const frag_ab*)&Bb[sw64(64 * wc + 16 * nt + li, 32 * kt + 8 * q4)];
#pragma unroll
        for (int mt = 0; mt < 4; ++mt)
#pragma unroll
          for (int nt = 0; nt < 4; ++nt)
            if (64 * wc + 16 * nt <= 64 * wr + 16 * mt + 15)
              accP[mt][nt] = __builtin_amdgcn_mfma_f32_16x16x32_bf16(af[mt], bf_[nt], accP[mt][nt], 0, 0, 0);
      }
    }
  }
  __syncthreads();  // all QP (Qs) reads done -> safe to overwrite with P
  // masked P (s<=t) -> QP
#pragma unroll
  for (int mt = 0; mt < 4; ++mt)
#pragma unroll
    for (int nt = 0; nt < 4; ++nt) {
      const int t0 = 64 * wr + 16 * mt + 4 * q4;
      const int s = 64 * wc + 16 * nt + li;
#pragma unroll
      for (int r = 0; r < 4; ++r) {
        const int t = t0 + r;
        QP[sw128(t, s)] = (s <= t) ? f2bf(accP[mt][nt][r]) : (unsigned short)0;
      }
    }

  // ---- GEMM2: accO += P x V  (V^T staged into Bb) ----
  for (int half = 0; half < 2; ++half) {
    __syncthreads();  // P visible / Bb reads done
#pragma unroll
    for (int it = 0; it < 8; ++it) {
      const int sl = (tid & 15) | ((it & 3) << 4);
      const int c0 = ((tid >> 4) | ((it >> 2) << 4)) << 2;
      const int s = 64 * half + sl;
      const float4 v4v = *(const float4*)(vg + cbase + (size_t)s * RS + c0);
      Bb[sw64(c0 + 0, sl)] = f2bf(v4v.x);
      Bb[sw64(c0 + 1, sl)] = f2bf(v4v.y);
      Bb[sw64(c0 + 2, sl)] = f2bf(v4v.z);
      Bb[sw64(c0 + 3, sl)] = f2bf(v4v.w);
    }
    __syncthreads();
#pragma unroll
    for (int kt = 0; kt < 2; ++kt) {
      const int ktg = 2 * half + kt;
      if (32 * ktg > 64 * wr + 63) continue;
      frag_ab af[4], bf_[4];
#pragma unroll
      for (int mt = 0; mt < 4; ++mt)
        af[mt] = *(const frag_ab*)&QP[sw128(64 * wr + 16 * mt + li, 32 * ktg + 8 * q4)];
#pragma unroll
      for (int nt = 0; nt < 4; ++nt)
        bf_[nt] = *(const frag_ab*)&Bb[sw64(64 * wc + 16 * nt + li, 32 * kt + 8 * q4)];
#pragma unroll
      for (int mt = 0; mt < 4; ++mt)
#pragma unroll
        for (int nt = 0; nt < 4; ++nt)
          if (32 * ktg <= 64 * wr + 16 * mt + 15)
            accO[mt][nt] = __builtin_amdgcn_mfma_f32_16x16x32_bf16(af[mt], bf_[nt], accO[mt][nt], 0, 0, 0);
    }
  }
  // store O fp32 (single write, no RMW)
#pragma unroll
  for (int mt = 0; mt < 4; ++mt)
#pragma unroll
    for (int nt = 0; nt < 4; ++nt)
#pragma unroll
      for (int r = 0; r < 4; ++r) {
        const int t = 64 * wr + 16 * mt + 4 * q4 + r;
        const int dv = 64 * wc + 16 * nt + li;
        o[cbase + (size_t)t * RS + dv] = accO[mt][nt][r];
      }
}

extern "C" void kernel_launch(void* const* d_in, const int* in_sizes, int n_in,
                              void* d_out, int out_size, void* d_ws, size_t ws_size,
                              hipStream_t stream) {
  const float* q = (const float*)d_in[0];
  const float* k = (const float*)d_in[1];
  const float* v = (const float*)d_in[2];
  float* o = (float*)d_out;
  unsigned short* st = (unsigned short*)d_ws;  // 32 MiB
  hipLaunchKernelGGL(phA_state, dim3(BHt * 8 * NSEG), dim3(256), 0, stream, k, v, st);
  hipLaunchKernelGGL(phFix, dim3(BHt * 8), dim3(256), 0, stream, st);
  hipLaunchKernelGGL(phB_out, dim3(BHt * NCH), dim3(256), 0, stream, q, k, v, st, o);
}

// Round 8
// 268.201 us; speedup vs baseline: 1.1980x; 1.0677x over previous
//
#include <hip/hip_runtime.h>

// Chunked linear attention (causal, unnormalized), bf16 MFMA, fp32 I/O.
// R11: phB widened to 512 threads (8 waves, 2x4 wave grid, 64x32 band/wave).
//   Same 128x128 tile, same stage order, same LDS (48 KB -> 3 blocks/CU);
//   resident waves/CU 12 -> 24, per-thread staging halved, acc regs halved.
//   phA: split-scan (unchanged): grid bh x slice x seg, NSEG=2, CPS=8.
//   phFix (unchanged): slot8 <- T_0; slots 9..15 <- local + T_0.
// B=4 S=2048 H=16 D=128. ws: 64*16*128*128 bf16 = 32 MiB.

#define Bc 4
#define Sq 2048
#define Hh 16
#define Dd 128
#define RS (Hh * Dd)      // 2048
#define Cc 128
#define NCH (Sq / Cc)     // 16
#define BHt (Bc * Hh)     // 64
#define NSEG 2
#define CPS (NCH / NSEG)  // 8
#define SCALE 0.08838834764831845f

using frag_ab = __attribute__((ext_vector_type(8))) short;  // 8 bf16
using frag_cd = __attribute__((ext_vector_type(4))) float;  // 4 fp32

__device__ __forceinline__ unsigned short f2bf(float f) {
  union { float f; unsigned u; } x; x.f = f;
  unsigned r = x.u + 0x7FFFu + ((x.u >> 16) & 1u);  // RNE
  return (unsigned short)(r >> 16);
}
__device__ __forceinline__ float bf2f(unsigned short u) {
  union { unsigned u; float f; } x; x.u = ((unsigned)u) << 16;
  return x.f;
}
// swizzles: permute 8-element (16 B) blocks within a row -> frag b128 reads
// stay contiguous; writes spread across banks.
__device__ __forceinline__ int sw64(int r, int c) {
  return r * 64 + ((((c >> 3) ^ (r & 7)) << 3) | (c & 7));
}
__device__ __forceinline__ int sw128(int r, int c) {
  return r * 128 + ((((c >> 3) ^ (r & 15)) << 3) | (c & 7));
}
__device__ __forceinline__ int swKT(int dk, int t) {  // [dk 128][t 128]
  return dk * 128 + ((((t >> 3) ^ (dk ^ (dk >> 4))) & 15) << 3) + (t & 7);
}
__device__ __forceinline__ int swVT(int dv, int t) {  // [dv 16][t 128]
  return dv * 128 + ((((t >> 3) ^ dv) & 15) << 3) + (t & 7);
}

// ---------- phA: split scan. Block = (bh, slice, seg); scans CPS chunks ----
// bid layout: bh low 6 bits (XCD-colocate), slice bits 6-8, seg bit 9.
__global__ __launch_bounds__(256) void phA_state(const float* __restrict__ kg,
                                                 const float* __restrict__ vg,
                                                 unsigned short* __restrict__ st) {
  __shared__ unsigned short KT[128 * 128];  // 32 KB [dk][t]
  __shared__ unsigned short VT[16 * 128];   //  4 KB [dv][t]
  const int tid = threadIdx.x;
  const int bh = blockIdx.x & 63;
  const int slice = (blockIdx.x >> 6) & 7;
  const int seg = blockIdx.x >> 9;
  const int b = bh >> 4, h = bh & 15;
  const int dv0 = slice * 16;
  const size_t base = (size_t)b * Sq * RS + (size_t)h * Dd;
  const int w = tid >> 6, L = tid & 63, li = L & 15, q4 = L >> 4;
  const int kdk0 = (tid & 31) * 4;
  const int ktg4 = (tid >> 5) * 4;
  const int vdv0l = (tid & 3) * 4;
  const int vt0 = (tid >> 2) * 2;

  float4 rk[4][4];
  float4 rv[2];
  auto prefetch = [&](int n) {
    const size_t t0g = (size_t)n * Cc;
#pragma unroll
    for (int p = 0; p < 4; ++p) {
      const int t0 = p * 32 + ktg4;
#pragma unroll
      for (int i = 0; i < 4; ++i)
        rk[p][i] = *(const float4*)(kg + base + (t0g + t0 + i) * (size_t)RS + kdk0);
    }
#pragma unroll
    for (int i = 0; i < 2; ++i)
      rv[i] = *(const float4*)(vg + base + (t0g + vt0 + i) * (size_t)RS + dv0 + vdv0l);
  };

  frag_cd acc[2];
  acc[0] = (frag_cd){0.f, 0.f, 0.f, 0.f};
  acc[1] = (frag_cd){0.f, 0.f, 0.f, 0.f};
  const int n0 = seg * CPS;
  prefetch(n0);
  const size_t sbb = (size_t)bh * NCH * (128 * 128);

  auto store_acc = [&](int slot) {
    const size_t sb = sbb + (size_t)slot * (128 * 128);
#pragma unroll
    for (int nt = 0; nt < 2; ++nt)
#pragma unroll
      for (int r = 0; r < 4; ++r) {
        const int dv = dv0 + 4 * q4 + r;
        const int dk = 32 * w + 16 * nt + li;
        st[sb + (size_t)dv * 128 + dk] = f2bf(acc[nt][r]);
      }
  };

  for (int j = 0; j < CPS; ++j) {
    __syncthreads();  // prev chunk's frag reads done
#pragma unroll
    for (int p = 0; p < 4; ++p) {
      const int t0 = p * 32 + ktg4;
#pragma unroll
      for (int jj = 0; jj < 4; ++jj) {
        ushort4 u;
        u.x = f2bf(((const float*)&rk[p][0])[jj]);
        u.y = f2bf(((const float*)&rk[p][1])[jj]);
        u.z = f2bf(((const float*)&rk[p][2])[jj]);
        u.w = f2bf(((const float*)&rk[p][3])[jj]);
        *(ushort4*)&KT[swKT(kdk0 + jj, t0)] = u;
      }
    }
#pragma unroll
    for (int jj = 0; jj < 4; ++jj) {
      ushort2 u;
      u.x = f2bf(((const float*)&rv[0])[jj]);
      u.y = f2bf(((const float*)&rv[1])[jj]);
      *(ushort2*)&VT[swVT(vdv0l + jj, vt0)] = u;
    }
    if (j + 1 < CPS) prefetch(n0 + j + 1);  // HBM latency hides under LDS+MFMA
    __syncthreads();
    if (j > 0) store_acc(n0 + j);  // local EXCLUSIVE prefix
#pragma unroll
    for (int kt = 0; kt < 4; ++kt) {
      frag_ab af = *(const frag_ab*)&VT[swVT(li, 32 * kt + 8 * q4)];
#pragma unroll
      for (int nt = 0; nt < 2; ++nt) {
        frag_ab bf = *(const frag_ab*)&KT[swKT(32 * w + 16 * nt + li, 32 * kt + 8 * q4)];
        acc[nt] = __builtin_amdgcn_mfma_f32_16x16x32_bf16(af, bf, acc[nt], 0, 0, 0);
      }
    }
  }
  if (seg + 1 < NSEG) store_acc(n0);  // segment total T_0 -> slot 0
}

// ---------- phFix: slots 8..15 -> true exclusive prefixes ----------
// Block = (bh, slot n in 8..15). slot8 <- T_0 (slot0 copy);
// slots 9..15 <- local + T_0 (bf16 pairs summed in fp32, repacked).
__global__ __launch_bounds__(256) void phFix(unsigned short* __restrict__ st) {
  const int bh = blockIdx.x & 63, n8 = blockIdx.x >> 6;  // 0..7
  const int n = 8 + n8;
  const int tid = threadIdx.x;
  const size_t b0 = ((size_t)(bh * NCH + 0)) << 14;
  const size_t bn = ((size_t)(bh * NCH + n)) << 14;
#pragma unroll
  for (int i = 0; i < 8; ++i) {
    const size_t off = (size_t)i * 2048 + tid * 8;
    const uint4 t0 = *(const uint4*)(st + b0 + off);
    if (n8 == 0) {
      *(uint4*)(st + bn + off) = t0;
    } else {
      const uint4 ln = *(const uint4*)(st + bn + off);
      const unsigned a[4] = {ln.x, ln.y, ln.z, ln.w};
      const unsigned c[4] = {t0.x, t0.y, t0.z, t0.w};
      unsigned pk[4];
#pragma unroll
      for (int e = 0; e < 4; ++e) {
        const float lo = bf2f((unsigned short)(a[e] & 0xFFFFu)) +
                         bf2f((unsigned short)(c[e] & 0xFFFFu));
        const float hi = bf2f((unsigned short)(a[e] >> 16)) +
                         bf2f((unsigned short)(c[e] >> 16));
        pk[e] = (unsigned)f2bf(lo) | ((unsigned)f2bf(hi) << 16);
      }
      uint4 out; out.x = pk[0]; out.y = pk[1]; out.z = pk[2]; out.w = pk[3];
      *(uint4*)(st + bn + off) = out;
    }
  }
}

// ---------- phB: O = Qs*H_n + tril(Qs*K^T)*V, 512 threads ----------
// 8 waves, wave w: wr=w>>2 owns rows [64wr,64wr+64), wc=w&3 owns cols
// [32wc,32wc+32). Slot n holds TRUE exclusive prefix (phFix); n==0 skips
// the H-GEMM. n is block-uniform -> barriers uniform.
__global__ __launch_bounds__(512) void phB_out(const float* __restrict__ qg,
                                               const float* __restrict__ kg,
                                               const float* __restrict__ vg,
                                               const unsigned short* __restrict__ st,
                                               float* __restrict__ o) {
  __shared__ unsigned short QP[128 * 128];  // 32 KB: Qs, later P
  __shared__ unsigned short Bb[128 * 64];   // 16 KB: H / K / V^T halves
  const int tid = threadIdx.x;
  const int bid = blockIdx.x;
  const int bh = bid >> 4, n = bid & 15;
  const int b = bh >> 4, h = bh & 15;
  const size_t cbase = (size_t)b * Sq * RS + (size_t)n * Cc * RS + (size_t)h * Dd;
  const size_t sb = (size_t)(bh * 16 + n) * (128 * 128);
  const int w = tid >> 6, L = tid & 63;
  const int wr = w >> 2, wc = w & 3, li = L & 15, q4 = L >> 4;

  // stage Qs full (scaled) -> QP
#pragma unroll
  for (int it = 0; it < 8; ++it) {
    const int f = it * 512 + tid;
    const int t = f >> 5;
    const int c0 = (f & 31) << 2;
    const float4 q4v = *(const float4*)(qg + cbase + (size_t)t * RS + c0);
    ushort4 qu;
    qu.x = f2bf(q4v.x * SCALE); qu.y = f2bf(q4v.y * SCALE);
    qu.z = f2bf(q4v.z * SCALE); qu.w = f2bf(q4v.w * SCALE);
    *(ushort4*)&QP[sw128(t, c0)] = qu;
  }
  frag_cd accO[4][2], accP[4][2];
#pragma unroll
  for (int i = 0; i < 4; ++i)
#pragma unroll
    for (int j = 0; j < 2; ++j) {
      accO[i][j] = (frag_cd){0.f, 0.f, 0.f, 0.f};
      accP[i][j] = (frag_cd){0.f, 0.f, 0.f, 0.f};
    }

  // ---- H-GEMM: accO = Qs (from QP) x H  (H in ws is [dv][dk]) ----
  if (n) {
    for (int half = 0; half < 2; ++half) {
      __syncthreads();  // half0: QP visible; half1: Bb reads done
#pragma unroll
      for (int it = 0; it < 2; ++it) {
        const int f = it * 512 + tid;
        const int dv = f >> 3;
        const int c8 = (f & 7) << 3;
        const uint4 hv = *(const uint4*)(st + sb + (size_t)dv * 128 + 64 * half + c8);
        *(uint4*)&Bb[sw64(dv, c8)] = hv;
      }
      __syncthreads();
#pragma unroll
      for (int kt = 0; kt < 2; ++kt) {
        const int ktg = 2 * half + kt;
        frag_ab af[4], bf_[2];
#pragma unroll
        for (int mt = 0; mt < 4; ++mt)
          af[mt] = *(const frag_ab*)&QP[sw128(64 * wr + 16 * mt + li, 32 * ktg + 8 * q4)];
#pragma unroll
        for (int nt = 0; nt < 2; ++nt)
          bf_[nt] = *(const frag_ab*)&Bb[sw64(32 * wc + 16 * nt + li, 32 * kt + 8 * q4)];
#pragma unroll
        for (int mt = 0; mt < 4; ++mt)
#pragma unroll
          for (int nt = 0; nt < 2; ++nt)
            accO[mt][nt] = __builtin_amdgcn_mfma_f32_16x16x32_bf16(af[mt], bf_[nt], accO[mt][nt], 0, 0, 0);
      }
    }
  }

  // ---- GEMM1: accP = Qs x K^T (triangle-skipped) ----
  for (int half = 0; half < 2; ++half) {
    __syncthreads();
#pragma unroll
    for (int it = 0; it < 4; ++it) {
      const int f = it * 512 + tid;
      const int t = f >> 4;
      const int c0 = (f & 15) << 2;
      const float4 k4v = *(const float4*)(kg + cbase + (size_t)t * RS + 64 * half + c0);
      ushort4 ku;
      ku.x = f2bf(k4v.x); ku.y = f2bf(k4v.y); ku.z = f2bf(k4v.z); ku.w = f2bf(k4v.w);
      *(ushort4*)&Bb[sw64(t, c0)] = ku;
    }
    __syncthreads();
    if (32 * wc <= 64 * wr + 63) {
#pragma unroll
      for (int kt = 0; kt < 2; ++kt) {
        const int ktg = 2 * half + kt;
        frag_ab af[4], bf_[2];
#pragma unroll
        for (int mt = 0; mt < 4; ++mt)
          af[mt] = *(const frag_ab*)&QP[sw128(64 * wr + 16 * mt + li, 32 * ktg + 8 * q4)];
#pragma unroll
        for (int nt = 0; nt < 2; ++nt)
          bf_[nt] = *(const frag_ab*)&Bb[sw64(32 * wc + 16 * nt + li, 32 * kt + 8 * q4)];
#pragma unroll
        for (int mt = 0; mt < 4; ++mt)
#pragma unroll
          for (int nt = 0; nt < 2; ++nt)
            if (32 * wc + 16 * nt <= 64 * wr + 16 * mt + 15)
              accP[mt][nt] = __builtin_amdgcn_mfma_f32_16x16x32_bf16(af[mt], bf_[nt], accP[mt][nt], 0, 0, 0);
      }
    }
  }
  __syncthreads();  // all QP (Qs) reads done -> safe to overwrite with P
  // masked P (s<=t) -> QP
#pragma unroll
  for (int mt = 0; mt < 4; ++mt)
#pragma unroll
    for (int nt = 0; nt < 2; ++nt) {
      const int t0 = 64 * wr + 16 * mt + 4 * q4;
      const int s = 32 * wc + 16 * nt + li;
#pragma unroll
      for (int r = 0; r < 4; ++r) {
        const int t = t0 + r;
        QP[sw128(t, s)] = (s <= t) ? f2bf(accP[mt][nt][r]) : (unsigned short)0;
      }
    }

  // ---- GEMM2: accO += P x V  (V^T staged into Bb) ----
  for (int half = 0; half < 2; ++half) {
    __syncthreads();  // P visible / Bb reads done
#pragma unroll
    for (int it = 0; it < 4; ++it) {
      const int e = (tid >> 8) | (it << 1);  // 0..7
      const int sl = (tid & 15) | ((e & 3) << 4);
      const int c0 = (((tid >> 4) & 15) | ((e >> 2) << 4)) << 2;
      const int s = 64 * half + sl;
      const float4 v4v = *(const float4*)(vg + cbase + (size_t)s * RS + c0);
      Bb[sw64(c0 + 0, sl)] = f2bf(v4v.x);
      Bb[sw64(c0 + 1, sl)] = f2bf(v4v.y);
      Bb[sw64(c0 + 2, sl)] = f2bf(v4v.z);
      Bb[sw64(c0 + 3, sl)] = f2bf(v4v.w);
    }
    __syncthreads();
#pragma unroll
    for (int kt = 0; kt < 2; ++kt) {
      const int ktg = 2 * half + kt;
      if (32 * ktg > 64 * wr + 63) continue;
      frag_ab af[4], bf_[2];
#pragma unroll
      for (int mt = 0; mt < 4; ++mt)
        af[mt] = *(const frag_ab*)&QP[sw128(64 * wr + 16 * mt + li, 32 * ktg + 8 * q4)];
#pragma unroll
      for (int nt = 0; nt < 2; ++nt)
        bf_[nt] = *(const frag_ab*)&Bb[sw64(32 * wc + 16 * nt + li, 32 * kt + 8 * q4)];
#pragma unroll
      for (int mt = 0; mt < 4; ++mt)
#pragma unroll
        for (int nt = 0; nt < 2; ++nt)
          if (32 * ktg <= 64 * wr + 16 * mt + 15)
            accO[mt][nt] = __builtin_amdgcn_mfma_f32_16x16x32_bf16(af[mt], bf_[nt], accO[mt][nt], 0, 0, 0);
    }
  }
  // store O fp32 (single write, no RMW)
#pragma unroll
  for (int mt = 0; mt < 4; ++mt)
#pragma unroll
    for (int nt = 0; nt < 2; ++nt)
#pragma unroll
      for (int r = 0; r < 4; ++r) {
        const int t = 64 * wr + 16 * mt + 4 * q4 + r;
        const int dv = 32 * wc + 16 * nt + li;
        o[cbase + (size_t)t * RS + dv] = accO[mt][nt][r];
      }
}

extern "C" void kernel_launch(void* const* d_in, const int* in_sizes, int n_in,
                              void* d_out, int out_size, void* d_ws, size_t ws_size,
                              hipStream_t stream) {
  const float* q = (const float*)d_in[0];
  const float* k = (const float*)d_in[1];
  const float* v = (const float*)d_in[2];
  float* o = (float*)d_out;
  unsigned short* st = (unsigned short*)d_ws;  // 32 MiB
  hipLaunchKernelGGL(phA_state, dim3(BHt * 8 * NSEG), dim3(256), 0, stream, k, v, st);
  hipLaunchKernelGGL(phFix, dim3(BHt * 8), dim3(256), 0, stream, st);
  hipLaunchKernelGGL(phB_out, dim3(BHt * NCH), dim3(512), 0, stream, q, k, v, st, o);
}